// Round 1
// baseline (15438.486 us; speedup 1.0000x reference)
//
#include <hip/hip_runtime.h>
#include <math.h>

#define N_PTS       40000
#define N_ANCH      4000     // ceil(0.1 * 40000)
#define KNN         20
#define FPS_BLOCKS  8
#define FPS_THREADS 1024
#define STRIDE      (FPS_BLOCKS * FPS_THREADS)   // 8192
#define PPT         5                             // 8192*5 = 40960 >= 40000

// ---------------------------------------------------------------------------
// Workspace layout (first 256 bytes zeroed via hipMemsetAsync each launch):
//   off   0 : double acc                 (loss accumulator)
//   off   8 : int    flag[8]             (per-block arrival flags, monotonic)
//   off  64 : double pval[2][8]          (parity-double-buffered partial max)
//   off 192 : int    pidx[2][8]
//   off 256 : int    anchors[4000]
// ---------------------------------------------------------------------------

// ======================= FPS (farthest point sampling) =====================
__global__ __launch_bounds__(FPS_THREADS) void fps_kernel(
    const float* __restrict__ pos,
    int* __restrict__ flag, double* __restrict__ pval, int* __restrict__ pidx,
    int* __restrict__ anchors) {
  const int t    = threadIdx.x;
  const int b    = blockIdx.x;
  const int gtid = b * FPS_THREADS + t;
  const int lane = t & 63;
  const int wave = t >> 6;

  float  px[PPT], py[PPT], pz[PPT];
  double md[PPT];

  const float a0x = pos[0], a0y = pos[1], a0z = pos[2];
#pragma unroll
  for (int k = 0; k < PPT; ++k) {
    int i = gtid + k * STRIDE;
    if (i < N_PTS) {
      px[k] = pos[3 * i]; py[k] = pos[3 * i + 1]; pz[k] = pos[3 * i + 2];
      double dx = (double)px[k] - (double)a0x;
      double dy = (double)py[k] - (double)a0y;
      double dz = (double)pz[k] - (double)a0z;
      md[k] = dx * dx + dy * dy + dz * dz;
    } else {
      px[k] = 0.f; py[k] = 0.f; pz[k] = 0.f;
      md[k] = -1.0e300;   // never selected
    }
  }
  if (b == 0 && t == 0) anchors[0] = 0;

  __shared__ double s_val[16];
  __shared__ int    s_idx[16];
  __shared__ float  s_anc[3];

  for (int iter = 1; iter < N_ANCH; ++iter) {
    // ---- thread-local argmax (ties -> lowest global index) ----
    double bv = -1.0e301; int bi = 0x7fffffff;
#pragma unroll
    for (int k = 0; k < PPT; ++k) {
      int i = gtid + k * STRIDE;
      bool better = (md[k] > bv) || (md[k] == bv && i < bi);
      bv = better ? md[k] : bv;
      bi = better ? i : bi;
    }
    // ---- wave argmax reduce ----
#pragma unroll
    for (int off = 32; off >= 1; off >>= 1) {
      double ov = __shfl_down(bv, off);
      int    oi = __shfl_down(bi, off);
      bool better = (ov > bv) || (ov == bv && oi < bi);
      bv = better ? ov : bv;
      bi = better ? oi : bi;
    }
    if (lane == 0) { s_val[wave] = bv; s_idx[wave] = bi; }
    __syncthreads();

    if (wave == 0) {
      // ---- cross-wave reduce (16 partials) ----
      bv = (lane < 16) ? s_val[lane] : -1.0e301;
      bi = (lane < 16) ? s_idx[lane] : 0x7fffffff;
#pragma unroll
      for (int off = 8; off >= 1; off >>= 1) {
        double ov = __shfl_down(bv, off);
        int    oi = __shfl_down(bi, off);
        bool better = (ov > bv) || (ov == bv && oi < bi);
        bv = better ? ov : bv;
        bi = better ? oi : bi;
      }
      const int par = iter & 1;
      if (lane == 0) {
        __hip_atomic_store(&pval[par * 8 + b], bv, __ATOMIC_RELAXED, __HIP_MEMORY_SCOPE_AGENT);
        __hip_atomic_store(&pidx[par * 8 + b], bi, __ATOMIC_RELAXED, __HIP_MEMORY_SCOPE_AGENT);
        __hip_atomic_store(&flag[b], iter, __ATOMIC_RELEASE, __HIP_MEMORY_SCOPE_AGENT);
      }
      // ---- lightweight grid barrier: poll all 8 flags ----
      if (lane < FPS_BLOCKS) {
        while (__hip_atomic_load(&flag[lane], __ATOMIC_ACQUIRE, __HIP_MEMORY_SCOPE_AGENT) < iter) {
          __builtin_amdgcn_s_sleep(2);
        }
      }
      // ---- redundant global winner reduce (all blocks agree) ----
      double v  = (lane < FPS_BLOCKS)
          ? __hip_atomic_load(&pval[par * 8 + lane], __ATOMIC_RELAXED, __HIP_MEMORY_SCOPE_AGENT)
          : -1.0e301;
      int    ix = (lane < FPS_BLOCKS)
          ? __hip_atomic_load(&pidx[par * 8 + lane], __ATOMIC_RELAXED, __HIP_MEMORY_SCOPE_AGENT)
          : 0x7fffffff;
#pragma unroll
      for (int off = 4; off >= 1; off >>= 1) {
        double ov = __shfl_down(v, off);
        int    oi = __shfl_down(ix, off);
        bool better = (ov > v) || (ov == v && oi < ix);
        v  = better ? ov : v;
        ix = better ? oi : ix;
      }
      if (lane == 0) {
        s_anc[0] = pos[3 * ix]; s_anc[1] = pos[3 * ix + 1]; s_anc[2] = pos[3 * ix + 2];
        if (b == 0) anchors[iter] = ix;
      }
    }
    __syncthreads();

    // ---- min-distance update vs new anchor (fp64, matches np ref) ----
    const float wx = s_anc[0], wy = s_anc[1], wz = s_anc[2];
#pragma unroll
    for (int k = 0; k < PPT; ++k) {
      double dx = (double)px[k] - (double)wx;
      double dy = (double)py[k] - (double)wy;
      double dz = (double)pz[k] - (double)wz;
      double d  = dx * dx + dy * dy + dz * dz;
      md[k] = fmin(md[k], d);
    }
  }
}

// ============== symmetric 3x3: eigenvector of largest eigenvalue ===========
__device__ static inline void eig3_maxvec(double xx, double xy, double xz,
                                          double yy, double yz, double zz,
                                          double& v0, double& v1, double& v2) {
  double q  = (xx + yy + zz) / 3.0;
  double p1 = xy * xy + xz * xz + yz * yz;
  double a00 = xx - q, a11 = yy - q, a22 = zz - q;
  double p2 = a00 * a00 + a11 * a11 + a22 * a22 + 2.0 * p1;
  if (p2 < 1e-300) { v0 = 1.0; v1 = 0.0; v2 = 0.0; return; }
  double p   = sqrt(p2 / 6.0);
  double inv = 1.0 / p;
  double b00 = a00 * inv, b01 = xy * inv, b02 = xz * inv;
  double b11 = a11 * inv, b12 = yz * inv, b22 = a22 * inv;
  double detB = b00 * (b11 * b22 - b12 * b12)
              - b01 * (b01 * b22 - b12 * b02)
              + b02 * (b01 * b12 - b11 * b02);
  double r = fmin(1.0, fmax(-1.0, detB * 0.5));
  double phi = acos(r) / 3.0;
  double lam = q + 2.0 * p * cos(phi);   // largest eigenvalue

  double r0x = xx - lam, r0y = xy,       r0z = xz;
  double r1x = xy,       r1y = yy - lam, r1z = yz;
  double r2x = xz,       r2y = yz,       r2z = zz - lam;
  // null vector of (M - lam I): cross of two rows, pick largest
  double c0x = r0y * r1z - r0z * r1y, c0y = r0z * r1x - r0x * r1z, c0z = r0x * r1y - r0y * r1x;
  double c1x = r0y * r2z - r0z * r2y, c1y = r0z * r2x - r0x * r2z, c1z = r0x * r2y - r0y * r2x;
  double c2x = r1y * r2z - r1z * r2y, c2y = r1z * r2x - r1x * r2z, c2z = r1x * r2y - r1y * r2x;
  double n0 = c0x * c0x + c0y * c0y + c0z * c0z;
  double n1 = c1x * c1x + c1y * c1y + c1z * c1z;
  double n2 = c2x * c2x + c2y * c2y + c2z * c2z;
  double bx = c0x, by = c0y, bz = c0z, bn = n0;
  if (n1 > bn) { bx = c1x; by = c1y; bz = c1z; bn = n1; }
  if (n2 > bn) { bx = c2x; by = c2y; bz = c2z; bn = n2; }
  if (bn < 1e-280) { v0 = 1.0; v1 = 0.0; v2 = 0.0; return; }
  double s = 1.0 / sqrt(bn);
  v0 = bx * s; v1 = by * s; v2 = bz * s;
}

// ================= KNN + principal direction + loss term ===================
__global__ __launch_bounds__(64) void knn_kernel(
    const float* __restrict__ pos, const float* __restrict__ vec_pred,
    const int* __restrict__ anchors, double* __restrict__ acc) {
  const int aidx = blockIdx.x;     // anchor ordinal i
  const int lane = threadIdx.x;
  const int ai   = anchors[aidx];
  const float ax = pos[3 * ai], ay = pos[3 * ai + 1], az = pos[3 * ai + 2];

  // per-lane top-20 smallest keys; key = (f32 dist bits << 32) | idx
  // (d >= 0 so float bit pattern is order-preserving; lex (d, idx) = u64 order)
  unsigned long long key[KNN];
#pragma unroll
  for (int s = 0; s < KNN; ++s) key[s] = ~0ull;
  unsigned long long kmax = ~0ull; int smax = 0;

  for (int k = 0; k < N_PTS / 64; ++k) {     // 625 candidates per lane
    int j = (k << 6) + lane;
    float dx = pos[3 * j] - ax, dy = pos[3 * j + 1] - ay, dz = pos[3 * j + 2] - az;
    float d  = dx * dx + dy * dy + dz * dz;
    unsigned long long nk = ((unsigned long long)__float_as_uint(d) << 32) | (unsigned int)j;
    if (nk < kmax) {
#pragma unroll
      for (int s = 0; s < KNN; ++s) key[s] = (s == smax) ? nk : key[s];
      kmax = 0ull; smax = 0;
#pragma unroll
      for (int s = 0; s < KNN; ++s) {
        bool g = key[s] > kmax;
        kmax = g ? key[s] : kmax;
        smax = g ? s : smax;
      }
    }
  }

  // merge 64 lane-local lists -> global top-20 (extract-min rounds)
  __shared__ unsigned long long lk[64 * KNN];
#pragma unroll
  for (int s = 0; s < KNN; ++s) lk[lane * KNN + s] = key[s];
  __syncthreads();
  __shared__ int w[KNN];
  for (int r = 0; r < KNN; ++r) {
    unsigned long long lmin = ~0ull; int ls = 0;
#pragma unroll
    for (int s = 0; s < KNN; ++s) {
      unsigned long long kk = lk[lane * KNN + s];
      bool l = kk < lmin;
      lmin = l ? kk : lmin;
      ls   = l ? s : ls;
    }
    unsigned long long mv = lmin; int ml = lane; int ms = ls;
#pragma unroll
    for (int off = 32; off >= 1; off >>= 1) {
      unsigned long long ov = __shfl_down(mv, off);
      int ol = __shfl_down(ml, off);
      int os = __shfl_down(ms, off);
      if (ov < mv) { mv = ov; ml = ol; ms = os; }
    }
    mv = __shfl(mv, 0); ml = __shfl(ml, 0); ms = __shfl(ms, 0);
    if (lane == ml) lk[ml * KNN + ms] = ~0ull;    // consume winner
    if (lane == 0)  w[r] = (int)(mv & 0xffffffffull);
    __syncthreads();
  }

  if (lane == 0) {
    // covariance of the 20 neighbors (fp64)
    double mx = 0, my = 0, mz = 0;
    for (int r = 0; r < KNN; ++r) {
      int p = w[r];
      mx += (double)pos[3 * p]; my += (double)pos[3 * p + 1]; mz += (double)pos[3 * p + 2];
    }
    mx /= KNN; my /= KNN; mz /= KNN;
    double xx = 0, xy = 0, xz = 0, yy = 0, yz = 0, zz = 0;
    for (int r = 0; r < KNN; ++r) {
      int p = w[r];
      double cx = (double)pos[3 * p]     - mx;
      double cy = (double)pos[3 * p + 1] - my;
      double cz = (double)pos[3 * p + 2] - mz;
      xx += cx * cx; xy += cx * cy; xz += cx * cz;
      yy += cy * cy; yz += cy * cz; zz += cz * cz;
    }
    double v0, v1, v2;
    eig3_maxvec(xx, xy, xz, yy, yz, zz, v0, v1, v2);

    double a0 = vec_pred[3 * aidx], a1 = vec_pred[3 * aidx + 1], a2 = vec_pred[3 * aidx + 2];
    double an = sqrt(a0 * a0 + a1 * a1 + a2 * a2);
    double bn = sqrt(v0 * v0 + v1 * v1 + v2 * v2);
    double denom = fmax(an, 1e-8) * fmax(bn, 1e-8);
    double c = fabs((a0 * v0 + a1 * v1 + a2 * v2) / denom);
    atomicAdd(acc, log(c + 1e-6));
  }
}

__global__ void finalize_kernel(const double* __restrict__ acc, float* __restrict__ out) {
  out[0] = (float)(-acc[0] / (double)N_ANCH);
}

// ===========================================================================
extern "C" void kernel_launch(void* const* d_in, const int* in_sizes, int n_in,
                              void* d_out, int out_size, void* d_ws, size_t ws_size,
                              hipStream_t stream) {
  (void)in_sizes; (void)n_in; (void)out_size; (void)ws_size;
  const float* vec_pred = (const float*)d_in[0];
  const float* pos      = (const float*)d_in[1];
  float* out = (float*)d_out;

  char* ws = (char*)d_ws;
  double* acc     = (double*)(ws + 0);
  int*    flag    = (int*)(ws + 8);
  double* pval    = (double*)(ws + 64);
  int*    pidx    = (int*)(ws + 192);
  int*    anchors = (int*)(ws + 256);

  hipMemsetAsync(d_ws, 0, 256, stream);   // zero acc + flags + partials
  hipLaunchKernelGGL(fps_kernel, dim3(FPS_BLOCKS), dim3(FPS_THREADS), 0, stream,
                     pos, flag, pval, pidx, anchors);
  hipLaunchKernelGGL(knn_kernel, dim3(N_ANCH), dim3(64), 0, stream,
                     pos, vec_pred, anchors, acc);
  hipLaunchKernelGGL(finalize_kernel, dim3(1), dim3(1), 0, stream, acc, out);
}